// Round 1
// baseline (740.008 us; speedup 1.0000x reference)
//
#include <hip/hip_runtime.h>
#include <math.h>

#define Bsz 8192
#define Dd  128
#define BM  64
#define BN  64
#define JSPLIT 4
#define LSTR 132   // 128 + 4 pad: row stride shifts banks by 4 -> worst 2-way aliasing (free)

static constexpr float INV_T = 1.0f / 0.07f;   // also used as the fixed logsumexp shift C

// ---------------- init: zero the compaction counters ----------------
__global__ void init_kernel(int* __restrict__ cnt) {
    if (threadIdx.x < 2) cnt[threadIdx.x] = 0;
}

// ---------------- prep: normalize, branch-select, compact ----------------
// one wave (64 lanes) per row; lane i owns float2 at d = 2i
__global__ __launch_bounds__(256) void prep_kernel(
    const float* __restrict__ fv, const float* __restrict__ fi,
    const float* __restrict__ v,  const float* __restrict__ vi,
    float* __restrict__ Xs, float* __restrict__ Y0, float* __restrict__ Y1,
    float* __restrict__ posArr, int* __restrict__ origArr, int* __restrict__ flagArr,
    float* __restrict__ lAcc, int* __restrict__ cnt)
{
    const int wave = threadIdx.x >> 6;
    const int lane = threadIdx.x & 63;
    const int b = blockIdx.x * 4 + wave;
    const int idx = b * 64 + lane;           // float2 index into [B,128]

    const float2 afv = ((const float2*)fv)[idx];
    const float2 afi = ((const float2*)fi)[idx];
    const float2 av  = ((const float2*)v )[idx];
    const float2 avi = ((const float2*)vi)[idx];

    float nfv = afv.x*afv.x + afv.y*afv.y;
    float nfi = afi.x*afi.x + afi.y*afi.y;
    float nv  = av.x*av.x   + av.y*av.y;
    float nvi = avi.x*avi.x + avi.y*avi.y;
    float dv  = afv.x*av.x  + afv.y*av.y;
    float di  = afi.x*avi.x + afi.y*avi.y;

    #pragma unroll
    for (int m = 1; m < 64; m <<= 1) {   // butterfly: every lane ends with totals
        nfv += __shfl_xor(nfv, m);
        nfi += __shfl_xor(nfi, m);
        nv  += __shfl_xor(nv,  m);
        nvi += __shfl_xor(nvi, m);
        dv  += __shfl_xor(dv,  m);
        di  += __shfl_xor(di,  m);
    }

    const float rnfv = 1.0f / fmaxf(sqrtf(nfv), 1e-12f);
    const float rnfi = 1.0f / fmaxf(sqrtf(nfi), 1e-12f);
    const float rnv  = 1.0f / fmaxf(sqrtf(nv ), 1e-12f);
    const float rnvi = 1.0f / fmaxf(sqrtf(nvi), 1e-12f);

    const float pos_v = dv * rnfv * rnv;
    const float pos_i = di * rnfi * rnvi;
    const bool useV = (pos_v >= pos_i);

    int p = 0;
    if (lane == 0) {
        if (useV) p = atomicAdd(&cnt[0], 1);           // group0 packs from front
        else      p = Bsz - 1 - atomicAdd(&cnt[1], 1); // group1 packs from back
    }
    p = __shfl(p, 0);

    const float sc = useV ? rnfv : rnfi;
    const float2 src = useV ? afv : afi;
    ((float2*)Xs)[p * 64 + lane] = make_float2(src.x * sc, src.y * sc);
    ((float2*)Y0)[idx] = make_float2(av.x  * rnv,  av.y  * rnv);
    ((float2*)Y1)[idx] = make_float2(avi.x * rnvi, avi.y * rnvi);

    if (lane == 0) {
        posArr[p]  = useV ? pos_v : pos_i;
        origArr[p] = b;
        flagArr[p] = useV ? 0 : 1;
        lAcc[b]    = 0.0f;   // zero the accumulator (ws is poisoned each launch)
    }
}

// ---------------- main: fused GEMM-row + exp-sum ----------------
// grid (B/BM, JSPLIT); 256 threads = (tx 0..15) x (ty 0..15)
// thread micro-tile: rows ty*4+r, cols tx+16*c  (4x4)
__global__ __launch_bounds__(256) void main_kernel(
    const float* __restrict__ Xs, const float* __restrict__ Y0, const float* __restrict__ Y1,
    const int* __restrict__ flagArr, float* __restrict__ lAcc)
{
    __shared__ float sX[BM * LSTR];
    __shared__ float sY[BN * LSTR];
    __shared__ int sFlag[BM];
    __shared__ int sHas[2];

    const int t  = threadIdx.x;
    const int tx = t & 15;
    const int ty = t >> 4;
    const int p0 = blockIdx.x * BM;
    const int j0base = blockIdx.y * (Bsz / JSPLIT);

    if (t < 2) sHas[t] = 0;
    __syncthreads();
    if (t < BM) {
        const int f = flagArr[p0 + t];
        sFlag[t] = f;
        atomicOr(&sHas[f], 1);
    }

    // load X tile (64 x 128) into LDS with padded stride
    for (int i = t; i < BM * 32; i += 256) {
        const int row = i >> 5, q = i & 31;
        const float4 val = ((const float4*)Xs)[(p0 + row) * 32 + q];
        *(float4*)&sX[row * LSTR + q * 4] = val;
    }
    __syncthreads();

    int fr[4];
    #pragma unroll
    for (int r = 0; r < 4; ++r) fr[r] = sFlag[ty * 4 + r];

    float lsum[4] = {0.f, 0.f, 0.f, 0.f};

    for (int phase = 0; phase < 2; ++phase) {
        if (!sHas[phase]) continue;           // pure blocks run exactly one phase
        const float* __restrict__ Y = phase ? Y1 : Y0;

        for (int jc = 0; jc < Bsz / JSPLIT; jc += BN) {
            const int j0 = j0base + jc;
            __syncthreads();
            for (int i = t; i < BN * 32; i += 256) {
                const int row = i >> 5, q = i & 31;
                const float4 val = ((const float4*)Y)[(j0 + row) * 32 + q];
                *(float4*)&sY[row * LSTR + q * 4] = val;
            }
            __syncthreads();

            float acc[4][4] = {};
            #pragma unroll 4
            for (int d = 0; d < Dd; d += 4) {
                float4 a[4], bb[4];
                #pragma unroll
                for (int r = 0; r < 4; ++r)
                    a[r] = *(const float4*)&sX[(ty * 4 + r) * LSTR + d];
                #pragma unroll
                for (int c = 0; c < 4; ++c)
                    bb[c] = *(const float4*)&sY[(tx + 16 * c) * LSTR + d];
                #pragma unroll
                for (int r = 0; r < 4; ++r)
                    #pragma unroll
                    for (int c = 0; c < 4; ++c)
                        acc[r][c] += a[r].x * bb[c].x + a[r].y * bb[c].y
                                   + a[r].z * bb[c].z + a[r].w * bb[c].w;
            }

            // fixed-shift exp accumulate: z = s/T, shift C = 1/T (max possible z)
            #pragma unroll
            for (int r = 0; r < 4; ++r) {
                if (fr[r] == phase) {
                    float s = 0.f;
                    #pragma unroll
                    for (int c = 0; c < 4; ++c)
                        s += __expf(acc[r][c] * INV_T - INV_T);
                    lsum[r] += s;
                }
            }
        }
    }

    // reduce across the 16 tx lanes (xor bits 0..3 stay inside the wave)
    #pragma unroll
    for (int m = 1; m < 16; m <<= 1)
        #pragma unroll
        for (int r = 0; r < 4; ++r)
            lsum[r] += __shfl_xor(lsum[r], m);

    if (tx == 0) {
        #pragma unroll
        for (int r = 0; r < 4; ++r)
            atomicAdd(&lAcc[p0 + ty * 4 + r], lsum[r]);
    }
}

// ---------------- finish: loss in original row order ----------------
__global__ __launch_bounds__(256) void finish_kernel(
    const float* __restrict__ lAcc, const float* __restrict__ posArr,
    const int* __restrict__ origArr, float* __restrict__ out)
{
    const int p = blockIdx.x * 256 + threadIdx.x;
    out[origArr[p]] = logf(lAcc[p]) + INV_T - posArr[p] * INV_T;
}

// ---------------- launch ----------------
extern "C" void kernel_launch(void* const* d_in, const int* in_sizes, int n_in,
                              void* d_out, int out_size, void* d_ws, size_t ws_size,
                              hipStream_t stream)
{
    const float* fv = (const float*)d_in[0];
    const float* fi = (const float*)d_in[1];
    const float* v  = (const float*)d_in[2];
    const float* vi = (const float*)d_in[3];
    float* out = (float*)d_out;

    float* Xs     = (float*)d_ws;        // [B,128] selected+normalized left vectors (compacted)
    float* Y0     = Xs + Bsz * Dd;       // [B,128] normalized v
    float* Y1     = Y0 + Bsz * Dd;       // [B,128] normalized vi
    float* posArr = Y1 + Bsz * Dd;       // [B] positive logit (by compacted index)
    float* lAcc   = posArr + Bsz;        // [B] exp-sum accumulator (by compacted index)
    int*  origArr = (int*)(lAcc + Bsz);  // [B] compacted -> original row
    int*  flagArr = origArr + Bsz;       // [B] flavor per compacted row
    int*  cnt     = flagArr + Bsz;       // [2] compaction counters

    hipLaunchKernelGGL(init_kernel, dim3(1), dim3(64), 0, stream, cnt);
    hipLaunchKernelGGL(prep_kernel, dim3(Bsz / 4), dim3(256), 0, stream,
                       fv, fi, v, vi, Xs, Y0, Y1, posArr, origArr, flagArr, lAcc, cnt);
    hipLaunchKernelGGL(main_kernel, dim3(Bsz / BM, JSPLIT), dim3(256), 0, stream,
                       Xs, Y0, Y1, flagArr, lAcc);
    hipLaunchKernelGGL(finish_kernel, dim3(Bsz / 256), dim3(256), 0, stream,
                       lAcc, posArr, origArr, out);
}

// Round 2
// 221.064 us; speedup vs baseline: 3.3475x; 3.3475x over previous
//
#include <hip/hip_runtime.h>
#include <math.h>

#define Bsz 8192
#define Dd  128
#define BM  128          // rows per block tile (compacted X rows)
#define BN  64           // cols per Y tile
#define JSPLIT 8         // j-range splits -> grid.y
#define LSTRB 136        // LDS row stride in bf16 elems: 272 B -> 4-bank shift/row, 16B aligned

typedef __attribute__((ext_vector_type(8))) short short8;   // 8 bf16 = 4 VGPR (MFMA A/B frag)
typedef __attribute__((ext_vector_type(4))) float float4v;  // MFMA C/D frag

static constexpr float INV_T = 1.0f / 0.07f;  // logit scale; also the fixed logsumexp shift C

// RNE float->bf16 pack (x -> low16, y -> high16)
static __device__ inline unsigned pack_bf16(float x, float y) {
    union { float f; unsigned u; } a, b;
    a.f = x; b.f = y;
    unsigned ra = a.u + 0x7FFF + ((a.u >> 16) & 1);
    unsigned rb = b.u + 0x7FFF + ((b.u >> 16) & 1);
    return (ra >> 16) | (rb & 0xFFFF0000u);
}

// ---------------- init: zero the compaction counters ----------------
__global__ void init_kernel(int* __restrict__ cnt) {
    if (threadIdx.x < 2) cnt[threadIdx.x] = 0;
}

// ---------------- prep: normalize, branch-select, compact, cast bf16 -------
// one wave per row; lane i owns float2 at d = 2i
__global__ __launch_bounds__(256) void prep_kernel(
    const float* __restrict__ fv, const float* __restrict__ fi,
    const float* __restrict__ v,  const float* __restrict__ vi,
    unsigned* __restrict__ Xb, unsigned* __restrict__ Y0b, unsigned* __restrict__ Y1b,
    float* __restrict__ posArr, int* __restrict__ origArr, int* __restrict__ flagArr,
    float* __restrict__ lAcc, int* __restrict__ cnt)
{
    const int wave = threadIdx.x >> 6;
    const int lane = threadIdx.x & 63;
    const int b = blockIdx.x * 4 + wave;
    const int idx = b * 64 + lane;           // float2 index into [B,128]

    const float2 afv = ((const float2*)fv)[idx];
    const float2 afi = ((const float2*)fi)[idx];
    const float2 av  = ((const float2*)v )[idx];
    const float2 avi = ((const float2*)vi)[idx];

    float nfv = afv.x*afv.x + afv.y*afv.y;
    float nfi = afi.x*afi.x + afi.y*afi.y;
    float nv  = av.x*av.x   + av.y*av.y;
    float nvi = avi.x*avi.x + avi.y*avi.y;
    float dv  = afv.x*av.x  + afv.y*av.y;
    float di  = afi.x*avi.x + afi.y*avi.y;

    #pragma unroll
    for (int m = 1; m < 64; m <<= 1) {
        nfv += __shfl_xor(nfv, m);
        nfi += __shfl_xor(nfi, m);
        nv  += __shfl_xor(nv,  m);
        nvi += __shfl_xor(nvi, m);
        dv  += __shfl_xor(dv,  m);
        di  += __shfl_xor(di,  m);
    }

    const float rnfv = 1.0f / fmaxf(sqrtf(nfv), 1e-12f);
    const float rnfi = 1.0f / fmaxf(sqrtf(nfi), 1e-12f);
    const float rnv  = 1.0f / fmaxf(sqrtf(nv ), 1e-12f);
    const float rnvi = 1.0f / fmaxf(sqrtf(nvi), 1e-12f);

    const float pos_v = dv * rnfv * rnv;
    const float pos_i = di * rnfi * rnvi;
    const bool useV = (pos_v >= pos_i);

    int p = 0;
    if (lane == 0) {
        if (useV) p = atomicAdd(&cnt[0], 1);           // flavor0 packs from front
        else      p = Bsz - 1 - atomicAdd(&cnt[1], 1); // flavor1 packs from back
    }
    p = __shfl(p, 0);

    const float sc = useV ? rnfv : rnfi;
    const float2 src = useV ? afv : afi;
    Xb [p * 64 + lane] = pack_bf16(src.x * sc,  src.y * sc);
    Y0b[idx]           = pack_bf16(av.x  * rnv, av.y  * rnv);
    Y1b[idx]           = pack_bf16(avi.x * rnvi, avi.y * rnvi);

    if (lane == 0) {
        posArr[p]  = useV ? pos_v : pos_i;
        origArr[p] = b;
        flagArr[p] = useV ? 0 : 1;
        lAcc[p]    = 0.0f;
    }
}

// ---------------- main: bf16 MFMA GEMM-row + fused exp-sum ----------------
// grid (Bsz/BM, JSPLIT), 256 threads = 4 waves.
// Wave w owns rows [w*32, w*32+32) of the block's X tile (2 row-tiles of 16).
// A-frag layout: A[m=lane&15][k=quad*8+j]; C/D: col=lane&15, row=quad*4+reg.
__global__ __launch_bounds__(256, 2) void main_kernel(
    const unsigned short* __restrict__ Xb,
    const unsigned short* __restrict__ Y0b, const unsigned short* __restrict__ Y1b,
    const int* __restrict__ flagArr, float* __restrict__ lAcc)
{
    __shared__ unsigned short sX[BM * LSTRB];   // 34816 B
    __shared__ unsigned short sY[BN * LSTRB];   // 17408 B
    __shared__ int sFlag[BM];
    __shared__ int sHas[2];

    const int t    = threadIdx.x;
    const int wave = t >> 6;
    const int lane = t & 63;
    const int quad = lane >> 4;
    const int mrow = lane & 15;
    const int p0   = blockIdx.x * BM;
    const int j0   = blockIdx.y * (Bsz / JSPLIT);

    if (t < 2) sHas[t] = 0;
    __syncthreads();
    if (t < BM) {
        const int f = flagArr[p0 + t];
        sFlag[t] = f;
        atomicOr(&sHas[f], 1);
    }

    // stage X tile: 128 rows x 256 B; thread handles 16B chunk (row = i>>4, chunk = i&15)
    for (int i = t; i < BM * 16; i += 256) {
        const int row = i >> 4, ch = i & 15;
        const uint4 val = ((const uint4*)Xb)[(p0 + row) * 16 + ch];
        *(uint4*)&sX[row * LSTRB + ch * 8] = val;
    }
    __syncthreads();

    // persistent A fragments: rt in {0,1}, kc in {0..3} (K chunks of 32)
    short8 afr[2][4];
    #pragma unroll
    for (int rt = 0; rt < 2; ++rt)
        #pragma unroll
        for (int kc = 0; kc < 4; ++kc)
            afr[rt][kc] = *(const short8*)&sX[(wave * 32 + rt * 16 + mrow) * LSTRB + kc * 32 + quad * 8];

    // per-lane output-row flags (C/D row = quad*4 + r)
    int fr[2][4];
    #pragma unroll
    for (int rt = 0; rt < 2; ++rt)
        #pragma unroll
        for (int r = 0; r < 4; ++r)
            fr[rt][r] = sFlag[wave * 32 + rt * 16 + quad * 4 + r];

    float rowsum[2][4] = {};

    for (int phase = 0; phase < 2; ++phase) {
        if (!sHas[phase]) continue;       // flavor-pure blocks run exactly one phase
        const unsigned short* __restrict__ Yb = phase ? Y1b : Y0b;

        for (int jt = 0; jt < Bsz / JSPLIT; jt += BN) {
            __syncthreads();
            for (int i = t; i < BN * 16; i += 256) {
                const int row = i >> 4, ch = i & 15;
                const uint4 val = ((const uint4*)Yb)[(j0 + jt + row) * 16 + ch];
                *(uint4*)&sY[row * LSTRB + ch * 8] = val;
            }
            __syncthreads();

            float4v acc[2][4] = {};   // [rt][ct]
            #pragma unroll
            for (int kc = 0; kc < 4; ++kc) {
                short8 bfr[4];
                #pragma unroll
                for (int ct = 0; ct < 4; ++ct)
                    bfr[ct] = *(const short8*)&sY[(ct * 16 + mrow) * LSTRB + kc * 32 + quad * 8];
                #pragma unroll
                for (int rt = 0; rt < 2; ++rt)
                    #pragma unroll
                    for (int ct = 0; ct < 4; ++ct)
                        acc[rt][ct] = __builtin_amdgcn_mfma_f32_16x16x32_bf16(
                            afr[rt][kc], bfr[ct], acc[rt][ct], 0, 0, 0);
            }

            // fused exp-sum with fixed shift C = 1/T (z <= 1/T always)
            #pragma unroll
            for (int rt = 0; rt < 2; ++rt)
                #pragma unroll
                for (int r = 0; r < 4; ++r)
                    if (fr[rt][r] == phase) {
                        float s = 0.f;
                        #pragma unroll
                        for (int ct = 0; ct < 4; ++ct)
                            s += __expf(acc[rt][ct][r] * INV_T - INV_T);
                        rowsum[rt][r] += s;
                    }
        }
    }

    // reduce over the 16 col-lanes (same quad), then one atomic per row
    #pragma unroll
    for (int m = 1; m < 16; m <<= 1)
        #pragma unroll
        for (int rt = 0; rt < 2; ++rt)
            #pragma unroll
            for (int r = 0; r < 4; ++r)
                rowsum[rt][r] += __shfl_xor(rowsum[rt][r], m);

    if (mrow == 0) {
        #pragma unroll
        for (int rt = 0; rt < 2; ++rt)
            #pragma unroll
            for (int r = 0; r < 4; ++r)
                atomicAdd(&lAcc[p0 + wave * 32 + rt * 16 + quad * 4 + r], rowsum[rt][r]);
    }
}

// ---------------- finish: loss in original row order ----------------
__global__ __launch_bounds__(256) void finish_kernel(
    const float* __restrict__ lAcc, const float* __restrict__ posArr,
    const int* __restrict__ origArr, float* __restrict__ out)
{
    const int p = blockIdx.x * 256 + threadIdx.x;
    out[origArr[p]] = logf(lAcc[p]) + INV_T - posArr[p] * INV_T;
}

// ---------------- launch ----------------
extern "C" void kernel_launch(void* const* d_in, const int* in_sizes, int n_in,
                              void* d_out, int out_size, void* d_ws, size_t ws_size,
                              hipStream_t stream)
{
    const float* fv = (const float*)d_in[0];
    const float* fi = (const float*)d_in[1];
    const float* v  = (const float*)d_in[2];
    const float* vi = (const float*)d_in[3];
    float* out = (float*)d_out;

    unsigned short* Xb  = (unsigned short*)d_ws;   // [B,128] bf16, compacted+normalized X
    unsigned short* Y0b = Xb  + Bsz * Dd;          // [B,128] bf16, normalized v
    unsigned short* Y1b = Y0b + Bsz * Dd;          // [B,128] bf16, normalized vi
    float* posArr = (float*)(Y1b + Bsz * Dd);      // [B] positive logit (compacted idx)
    float* lAcc   = posArr + Bsz;                  // [B] exp-sum accumulator (compacted idx)
    int*  origArr = (int*)(lAcc + Bsz);            // [B] compacted -> original row
    int*  flagArr = origArr + Bsz;                 // [B] flavor per compacted row
    int*  cnt     = flagArr + Bsz;                 // [2] compaction counters

    hipLaunchKernelGGL(init_kernel, dim3(1), dim3(64), 0, stream, cnt);
    hipLaunchKernelGGL(prep_kernel, dim3(Bsz / 4), dim3(256), 0, stream,
                       fv, fi, v, vi, (unsigned*)Xb, (unsigned*)Y0b, (unsigned*)Y1b,
                       posArr, origArr, flagArr, lAcc, cnt);
    hipLaunchKernelGGL(main_kernel, dim3(Bsz / BM, JSPLIT), dim3(256), 0, stream,
                       Xb, Y0b, Y1b, flagArr, lAcc);
    hipLaunchKernelGGL(finish_kernel, dim3(Bsz / 256), dim3(256), 0, stream,
                       lAcc, posArr, origArr, out);
}

// Round 3
// 153.111 us; speedup vs baseline: 4.8331x; 1.4438x over previous
//
#include <hip/hip_runtime.h>
#include <math.h>

#define Bsz 8192
#define Dd  128
#define BM  128                         // rows per block tile
#define BN  64                          // cols per Y tile
#define JSPLIT 8                        // j-range splits -> grid.y (512 blocks total)
#define NTILES ((Bsz / JSPLIT) / BN)    // 16 Y tiles per block
#define LSTRB 136                       // LDS row stride (bf16): 272 B -> 4-bank shift, 16B aligned

typedef __attribute__((ext_vector_type(8))) short short8;   // 8 bf16 = 4 VGPR (MFMA A/B frag)
typedef __attribute__((ext_vector_type(4))) float float4v;  // MFMA C/D frag

static constexpr float INV_T = 1.0f / 0.07f;  // logit scale; also fixed logsumexp shift C

// RNE float->bf16 pack (x -> low16, y -> high16)
static __device__ inline unsigned pack_bf16(float x, float y) {
    union { float f; unsigned u; } a, b;
    a.f = x; b.f = y;
    unsigned ra = a.u + 0x7FFF + ((a.u >> 16) & 1);
    unsigned rb = b.u + 0x7FFF + ((b.u >> 16) & 1);
    return (ra >> 16) | (rb & 0xFFFF0000u);
}

// ---------------- init: zero the packed compaction counter ----------------
__global__ void init_kernel(unsigned long long* __restrict__ cnt) {
    if (threadIdx.x == 0) cnt[0] = 0ull;
}

// ---------------- prep: normalize, select, compact (1 packed atomic/block) ----
// 1024 threads = 16 waves = 16 rows per block; lane i owns float2 at d = 2i
__global__ __launch_bounds__(1024) void prep_kernel(
    const float* __restrict__ fv, const float* __restrict__ fi,
    const float* __restrict__ v,  const float* __restrict__ vi,
    unsigned* __restrict__ Xb, unsigned* __restrict__ Y0b, unsigned* __restrict__ Y1b,
    float* __restrict__ posArr, int* __restrict__ origArr, int* __restrict__ flagArr,
    float* __restrict__ lAcc, unsigned long long* __restrict__ cnt)
{
    __shared__ int sFlagL[16];
    __shared__ int sRank[16];
    __shared__ unsigned sBase[2];

    const int wave = threadIdx.x >> 6;
    const int lane = threadIdx.x & 63;
    const int b = blockIdx.x * 16 + wave;
    const int idx = b * 64 + lane;          // float2 index into [B,128]

    const float2 afv = ((const float2*)fv)[idx];
    const float2 afi = ((const float2*)fi)[idx];
    const float2 av  = ((const float2*)v )[idx];
    const float2 avi = ((const float2*)vi)[idx];

    float nfv = afv.x*afv.x + afv.y*afv.y;
    float nfi = afi.x*afi.x + afi.y*afi.y;
    float nv  = av.x*av.x   + av.y*av.y;
    float nvi = avi.x*avi.x + avi.y*avi.y;
    float dv  = afv.x*av.x  + afv.y*av.y;
    float di  = afi.x*avi.x + afi.y*avi.y;

    #pragma unroll
    for (int m = 1; m < 64; m <<= 1) {
        nfv += __shfl_xor(nfv, m);
        nfi += __shfl_xor(nfi, m);
        nv  += __shfl_xor(nv,  m);
        nvi += __shfl_xor(nvi, m);
        dv  += __shfl_xor(dv,  m);
        di  += __shfl_xor(di,  m);
    }

    const float rnfv = 1.0f / fmaxf(sqrtf(nfv), 1e-12f);
    const float rnfi = 1.0f / fmaxf(sqrtf(nfi), 1e-12f);
    const float rnv  = 1.0f / fmaxf(sqrtf(nv ), 1e-12f);
    const float rnvi = 1.0f / fmaxf(sqrtf(nvi), 1e-12f);

    const float pos_v = dv * rnfv * rnv;
    const float pos_i = di * rnfi * rnvi;
    const bool useV = (pos_v >= pos_i);
    const float pos = useV ? pos_v : pos_i;

    // Y writes don't depend on compaction index
    Y0b[idx] = pack_bf16(av.x  * rnv,  av.y  * rnv);
    Y1b[idx] = pack_bf16(avi.x * rnvi, avi.y * rnvi);

    if (lane == 0) sFlagL[wave] = useV ? 0 : 1;
    __syncthreads();

    // wave 0: block-local ranks + one packed 64-bit atomic for both counters
    if (threadIdx.x < 64) {
        const int f = (lane < 16) ? sFlagL[lane] : 2;
        const unsigned long long m0 = __ballot(f == 0);
        const unsigned long long m1 = __ballot(f == 1);
        if (lane == 0) {
            const unsigned long long add =
                (unsigned long long)__popcll(m0) | ((unsigned long long)__popcll(m1) << 32);
            const unsigned long long ret = atomicAdd(cnt, add);
            sBase[0] = (unsigned)(ret & 0xffffffffull);
            sBase[1] = (unsigned)(ret >> 32);
        }
        if (lane < 16) {
            const unsigned long long below = (1ull << lane) - 1ull;
            sRank[lane] = (f == 0) ? (int)__popcll(m0 & below) : (int)__popcll(m1 & below);
        }
    }
    __syncthreads();

    const int f  = sFlagL[wave];
    const int rk = sRank[wave];
    const int p  = (f == 0) ? (int)(sBase[0] + rk) : (Bsz - 1 - (int)(sBase[1] + rk));

    const float sc = useV ? rnfv : rnfi;
    const float2 src = useV ? afv : afi;
    Xb[p * 64 + lane] = pack_bf16(src.x * sc, src.y * sc);

    if (lane == 0) {
        posArr[p]  = pos;
        origArr[p] = b;
        flagArr[p] = f;
        lAcc[p]    = 0.0f;
    }
}

// ---------------- main: bf16 MFMA GEMM-row + fused exp-sum ----------------
// grid (Bsz/BM, JSPLIT), 256 threads = 4 waves in 2x2:
//   wr = wave>>1 owns rows [wr*64, wr*64+64); wc = wave&1 owns cols [wc*32, wc*32+32)
// A-frag: A[m=lane&15][k=quad*8+j]; C/D: col=lane&15, row=quad*4+reg.
// Double-buffered Y staging: prefetch tile jt+1 into regs during compute of jt.
__global__ __launch_bounds__(256, 2) void main_kernel(
    const unsigned short* __restrict__ Xb,
    const unsigned short* __restrict__ Y0b, const unsigned short* __restrict__ Y1b,
    const int* __restrict__ flagArr, float* __restrict__ lAcc)
{
    __shared__ unsigned short sX[BM * LSTRB];       // 34816 B
    __shared__ unsigned short sY[2][BN * LSTRB];    // 2 x 17408 B
    __shared__ int sFlag[BM];
    __shared__ int sHas[2];

    const int t    = threadIdx.x;
    const int wave = t >> 6;
    const int wr   = wave >> 1;
    const int wc   = wave & 1;
    const int lane = t & 63;
    const int quad = lane >> 4;
    const int mrow = lane & 15;
    const int p0   = blockIdx.x * BM;
    const int j0   = blockIdx.y * (Bsz / JSPLIT);

    if (t < 2) sHas[t] = 0;
    __syncthreads();
    if (t < BM) {
        const int f = flagArr[p0 + t];
        sFlag[t] = f;
        atomicOr(&sHas[f], 1);
    }

    // stage X tile: 128 rows x 256 B
    for (int i = t; i < BM * 16; i += 256) {
        const int row = i >> 4, ch = i & 15;
        *(uint4*)&sX[row * LSTRB + ch * 8] = ((const uint4*)Xb)[(p0 + row) * 16 + ch];
    }
    __syncthreads();

    // persistent A fragments: 4 row-tiles of 16 x 4 K-chunks of 32
    short8 afr[4][4];
    #pragma unroll
    for (int rt = 0; rt < 4; ++rt)
        #pragma unroll
        for (int kc = 0; kc < 4; ++kc)
            afr[rt][kc] = *(const short8*)&sX[(wr * 64 + rt * 16 + mrow) * LSTRB + kc * 32 + quad * 8];

    // per-lane row flags packed into a bitmask (bit rt*4+r), row = wr*64+rt*16+quad*4+r
    unsigned frmask = 0;
    #pragma unroll
    for (int rt = 0; rt < 4; ++rt)
        #pragma unroll
        for (int r = 0; r < 4; ++r)
            frmask |= (unsigned)sFlag[wr * 64 + rt * 16 + quad * 4 + r] << (rt * 4 + r);

    float rowsum[4][4] = {};

    for (int phase = 0; phase < 2; ++phase) {
        if (!sHas[phase]) continue;          // flavor-pure blocks run exactly one phase
        const unsigned short* __restrict__ Yb = phase ? Y1b : Y0b;

        uint4 nxt[4];
        // prologue: stage tile 0 into buf 0
        #pragma unroll
        for (int u = 0; u < 4; ++u) {
            const int i = t + u * 256, row = i >> 4, ch = i & 15;
            nxt[u] = ((const uint4*)Yb)[(j0 + row) * 16 + ch];
        }
        #pragma unroll
        for (int u = 0; u < 4; ++u) {
            const int i = t + u * 256, row = i >> 4, ch = i & 15;
            *(uint4*)&sY[0][row * LSTRB + ch * 8] = nxt[u];
        }

        for (int jt = 0; jt < NTILES; ++jt) {
            const int buf = jt & 1;
            if (jt + 1 < NTILES) {           // prefetch next tile into registers
                #pragma unroll
                for (int u = 0; u < 4; ++u) {
                    const int i = t + u * 256, row = i >> 4, ch = i & 15;
                    nxt[u] = ((const uint4*)Yb)[(j0 + (jt + 1) * BN + row) * 16 + ch];
                }
            }
            __syncthreads();                 // sY[buf] ready

            float4v acc[4][2] = {};          // [rt][ct]
            #pragma unroll
            for (int kc = 0; kc < 4; ++kc) {
                short8 bfr[2];
                #pragma unroll
                for (int ct = 0; ct < 2; ++ct)
                    bfr[ct] = *(const short8*)&sY[buf][(wc * 32 + ct * 16 + mrow) * LSTRB + kc * 32 + quad * 8];
                #pragma unroll
                for (int rt = 0; rt < 4; ++rt)
                    #pragma unroll
                    for (int ct = 0; ct < 2; ++ct)
                        acc[rt][ct] = __builtin_amdgcn_mfma_f32_16x16x32_bf16(
                            afr[rt][kc], bfr[ct], acc[rt][ct], 0, 0, 0);
            }

            // fused exp-sum, fixed shift C = 1/T (z <= 1/T always)
            #pragma unroll
            for (int rt = 0; rt < 4; ++rt)
                #pragma unroll
                for (int r = 0; r < 4; ++r)
                    if ((int)((frmask >> (rt * 4 + r)) & 1u) == phase)
                        rowsum[rt][r] += __expf(acc[rt][0][r] * INV_T - INV_T)
                                       + __expf(acc[rt][1][r] * INV_T - INV_T);

            if (jt + 1 < NTILES) {
                __syncthreads();             // all reads of sY[buf^1] (from jt-1) done
                #pragma unroll
                for (int u = 0; u < 4; ++u) {
                    const int i = t + u * 256, row = i >> 4, ch = i & 15;
                    *(uint4*)&sY[buf ^ 1][row * LSTRB + ch * 8] = nxt[u];
                }
            }
        }
    }

    // reduce over the 16 col-lanes of each quad
    #pragma unroll
    for (int m = 1; m < 16; m <<= 1)
        #pragma unroll
        for (int rt = 0; rt < 4; ++rt)
            #pragma unroll
            for (int r = 0; r < 4; ++r)
                rowsum[rt][r] += __shfl_xor(rowsum[rt][r], m);

    if (mrow == 0) {   // both wc waves contribute their col-half partial
        #pragma unroll
        for (int rt = 0; rt < 4; ++rt)
            #pragma unroll
            for (int r = 0; r < 4; ++r)
                atomicAdd(&lAcc[p0 + wr * 64 + rt * 16 + quad * 4 + r], rowsum[rt][r]);
    }
}

// ---------------- finish: loss in original row order ----------------
__global__ __launch_bounds__(256) void finish_kernel(
    const float* __restrict__ lAcc, const float* __restrict__ posArr,
    const int* __restrict__ origArr, float* __restrict__ out)
{
    const int p = blockIdx.x * 256 + threadIdx.x;
    out[origArr[p]] = logf(lAcc[p]) + INV_T - posArr[p] * INV_T;
}

// ---------------- launch ----------------
extern "C" void kernel_launch(void* const* d_in, const int* in_sizes, int n_in,
                              void* d_out, int out_size, void* d_ws, size_t ws_size,
                              hipStream_t stream)
{
    const float* fv = (const float*)d_in[0];
    const float* fi = (const float*)d_in[1];
    const float* v  = (const float*)d_in[2];
    const float* vi = (const float*)d_in[3];
    float* out = (float*)d_out;

    unsigned short* Xb  = (unsigned short*)d_ws;   // [B,128] bf16, compacted+normalized X
    unsigned short* Y0b = Xb  + Bsz * Dd;          // [B,128] bf16, normalized v
    unsigned short* Y1b = Y0b + Bsz * Dd;          // [B,128] bf16, normalized vi
    float* posArr = (float*)(Y1b + Bsz * Dd);      // [B] positive logit (compacted idx)
    float* lAcc   = posArr + Bsz;                  // [B] exp-sum accumulator (compacted idx)
    int*  origArr = (int*)(lAcc + Bsz);            // [B] compacted -> original row
    int*  flagArr = origArr + Bsz;                 // [B] flavor per compacted row
    unsigned long long* cnt = (unsigned long long*)(flagArr + Bsz);  // packed counters

    hipLaunchKernelGGL(init_kernel, dim3(1), dim3(64), 0, stream, cnt);
    hipLaunchKernelGGL(prep_kernel, dim3(Bsz / 16), dim3(1024), 0, stream,
                       fv, fi, v, vi, (unsigned*)Xb, (unsigned*)Y0b, (unsigned*)Y1b,
                       posArr, origArr, flagArr, lAcc, cnt);
    hipLaunchKernelGGL(main_kernel, dim3(Bsz / BM, JSPLIT), dim3(256), 0, stream,
                       Xb, Y0b, Y1b, flagArr, lAcc);
    hipLaunchKernelGGL(finish_kernel, dim3(Bsz / 256), dim3(256), 0, stream,
                       lAcc, posArr, origArr, out);
}

// Round 4
// 126.376 us; speedup vs baseline: 5.8556x; 1.2116x over previous
//
#include <hip/hip_runtime.h>
#include <math.h>

#define Bsz 8192
#define Dd  128
#define BM  128          // rows per main block; each wave handles ALL of them
#define JSPLIT 8         // grid.y: 8 j-splits -> 64x8 = 512 blocks (2/CU)

typedef __attribute__((ext_vector_type(8))) short short8;   // 8 bf16 = 4 VGPR
typedef __attribute__((ext_vector_type(4))) float float4v;  // MFMA C/D frag

static constexpr float INV_T = 1.0f / 0.07f;  // logit scale; also fixed logsumexp shift

// RNE float->bf16 pack (x -> low16, y -> high16)
static __device__ inline unsigned pack_bf16(float x, float y) {
    union { float f; unsigned u; } a, b;
    a.f = x; b.f = y;
    unsigned ra = a.u + 0x7FFF + ((a.u >> 16) & 1);
    unsigned rb = b.u + 0x7FFF + ((b.u >> 16) & 1);
    return (ra >> 16) | (rb & 0xFFFF0000u);
}

// ---------------- init: zero the packed compaction counter ----------------
__global__ void init_kernel(unsigned long long* __restrict__ cnt) {
    if (threadIdx.x == 0) cnt[0] = 0ull;
}

// ---------------- prep ----------------
// 1024 threads = 16 waves = 16 rows = exactly ONE 16-col fragment tile.
// Emits: Xb (row-major bf16, compacted), Yf0/Yf1 (B-fragment-ordered bf16):
//   Yf word layout: [tile g][kc][lane'=quad*16+n][w]  (1KB per (g,kc) block)
//   data at (lane', w): row n of tile, d = kc*32 + quad*8 + w*2 .. +2
__global__ __launch_bounds__(1024) void prep_kernel(
    const float* __restrict__ fv, const float* __restrict__ fi,
    const float* __restrict__ v,  const float* __restrict__ vi,
    unsigned* __restrict__ Xb, unsigned* __restrict__ Yf0, unsigned* __restrict__ Yf1,
    float* __restrict__ posArr, int* __restrict__ origArr, int* __restrict__ flagArr,
    float* __restrict__ lAcc, unsigned long long* __restrict__ cnt)
{
    __shared__ unsigned sT0[16 * 65];   // row-stride 65 words: conflict-free transpose
    __shared__ unsigned sT1[16 * 65];
    __shared__ int sFlagL[16];
    __shared__ int sRank[16];
    __shared__ unsigned sBase[2];

    const int t    = threadIdx.x;
    const int wave = t >> 6;
    const int lane = t & 63;
    const int b = blockIdx.x * 16 + wave;
    const int idx = b * 64 + lane;          // float2 index into [B,128]

    const float2 afv = ((const float2*)fv)[idx];
    const float2 afi = ((const float2*)fi)[idx];
    const float2 av  = ((const float2*)v )[idx];
    const float2 avi = ((const float2*)vi)[idx];

    float nfv = afv.x*afv.x + afv.y*afv.y;
    float nfi = afi.x*afi.x + afi.y*afi.y;
    float nv  = av.x*av.x   + av.y*av.y;
    float nvi = avi.x*avi.x + avi.y*avi.y;
    float dv  = afv.x*av.x  + afv.y*av.y;
    float di  = afi.x*avi.x + afi.y*avi.y;

    #pragma unroll
    for (int m = 1; m < 64; m <<= 1) {
        nfv += __shfl_xor(nfv, m);
        nfi += __shfl_xor(nfi, m);
        nv  += __shfl_xor(nv,  m);
        nvi += __shfl_xor(nvi, m);
        dv  += __shfl_xor(dv,  m);
        di  += __shfl_xor(di,  m);
    }

    const float rnfv = 1.0f / fmaxf(sqrtf(nfv), 1e-12f);
    const float rnfi = 1.0f / fmaxf(sqrtf(nfi), 1e-12f);
    const float rnv  = 1.0f / fmaxf(sqrtf(nv ), 1e-12f);
    const float rnvi = 1.0f / fmaxf(sqrtf(nvi), 1e-12f);

    const float pos_v = dv * rnfv * rnv;
    const float pos_i = di * rnfi * rnvi;
    const bool useV = (pos_v >= pos_i);
    const float pos = useV ? pos_v : pos_i;

    // stage Y rows (packed d-pair words) for the in-LDS fragment transpose
    sT0[wave * 65 + lane] = pack_bf16(av.x  * rnv,  av.y  * rnv);
    sT1[wave * 65 + lane] = pack_bf16(avi.x * rnvi, avi.y * rnvi);
    if (lane == 0) sFlagL[wave] = useV ? 0 : 1;
    __syncthreads();

    // wave 0: block-local ranks + ONE packed 64-bit atomic for both counters
    if (t < 64) {
        const int f = (lane < 16) ? sFlagL[lane] : 2;
        const unsigned long long m0 = __ballot(f == 0);
        const unsigned long long m1 = __ballot(f == 1);
        if (lane == 0) {
            const unsigned long long add =
                (unsigned long long)__popcll(m0) | ((unsigned long long)__popcll(m1) << 32);
            const unsigned long long ret = atomicAdd(cnt, add);
            sBase[0] = (unsigned)(ret & 0xffffffffull);
            sBase[1] = (unsigned)(ret >> 32);
        }
        if (lane < 16) {
            const unsigned long long below = (1ull << lane) - 1ull;
            sRank[lane] = (f == 0) ? (int)__popcll(m0 & below) : (int)__popcll(m1 & below);
        }
    }

    // fragment-ordered write-out: out word o = t of this tile (coalesced)
    {
        const int kc = t >> 8;
        const int lp = (t >> 2) & 63;          // lane' = quad*16 + n
        const int w  = t & 3;
        const int n  = lp & 15;
        const int s  = kc * 16 + (lp >> 4) * 4 + w;   // source d-pair (lane in sT row)
        Yf0[blockIdx.x * 1024 + t] = sT0[n * 65 + s];
        Yf1[blockIdx.x * 1024 + t] = sT1[n * 65 + s];
    }
    __syncthreads();

    const int f  = sFlagL[wave];
    const int rk = sRank[wave];
    const int p  = (f == 0) ? (int)(sBase[0] + rk) : (Bsz - 1 - (int)(sBase[1] + rk));

    const float sc = useV ? rnfv : rnfi;
    const float2 src = useV ? afv : afi;
    Xb[p * 64 + lane] = pack_bf16(src.x * sc, src.y * sc);

    if (lane == 0) {
        posArr[p]  = pos;
        origArr[p] = b;
        flagArr[p] = f;
        lAcc[p]    = 0.0f;
    }
}

// ---------------- main: barrier-free B-fragment streaming ----------------
// grid (Bsz/BM=64, JSPLIT=8), 256 threads = 4 waves.
// Each wave: ALL 128 block rows (afr[8][4] persistent) x 256 cols (16 tiles).
// A/B frag: [m|n = lane&15][k = quad*8+j]; C/D: col=lane&15, row=quad*4+reg.
// j-loop: reg-double-buffered global fragment loads, NO barriers.
__global__ __launch_bounds__(256, 2) void main_kernel(
    const unsigned short* __restrict__ Xb,
    const unsigned short* __restrict__ Yf0, const unsigned short* __restrict__ Yf1,
    const int* __restrict__ flagArr, float* __restrict__ lAcc)
{
    __shared__ unsigned sXf[8192];      // 32 KB: X tile in fragment order
    __shared__ int sFlag[BM];
    __shared__ int sHas[2];

    const int t    = threadIdx.x;
    const int wave = t >> 6;
    const int lane = t & 63;
    const int quad = lane >> 4;
    const int mrow = lane & 15;
    const int p0   = blockIdx.x * BM;

    if (t < 2) sHas[t] = 0;
    __syncthreads();
    if (t < BM) {
        const int f = flagArr[p0 + t];
        sFlag[t] = f;
        atomicOr(&sHas[f], 1);
    }

    // stage X tile into fragment order (coalesced global read, once per block):
    // src uint4 at (row = i>>4, ch = i&15) holds d = ch*8..ch*8+7 of row
    // dst slot: rt=row>>4, kc=ch>>2, lane'=(ch&3)*16 + (row&15)
    for (int it = 0; it < 8; ++it) {
        const int i = t + it * 256;
        const int row = i >> 4, ch = i & 15;
        const uint4 val = ((const uint4*)Xb)[(p0 + row) * 16 + ch];
        const int dst = (((row >> 4) * 4 + (ch >> 2)) * 64 + (ch & 3) * 16 + (row & 15)) * 4;
        *(uint4*)&sXf[dst] = val;
    }
    __syncthreads();

    // persistent A fragments: lane-linear reads, conflict-free
    short8 afr[8][4];
    #pragma unroll
    for (int rt = 0; rt < 8; ++rt)
        #pragma unroll
        for (int kc = 0; kc < 4; ++kc)
            afr[rt][kc] = *(const short8*)&sXf[((rt * 4 + kc) * 64 + lane) * 4];

    // per-lane row flags: bit rt*4+r for row rt*16 + quad*4 + r
    unsigned frmask = 0;
    #pragma unroll
    for (int rt = 0; rt < 8; ++rt)
        #pragma unroll
        for (int r = 0; r < 4; ++r)
            frmask |= (unsigned)sFlag[rt * 16 + quad * 4 + r] << (rt * 4 + r);

    float rowsum[8][4] = {};
    const int g0 = blockIdx.y * 64 + wave * 16;   // first col-tile (of 512) for this wave

    for (int phase = 0; phase < 2; ++phase) {
        if (!sHas[phase]) continue;               // flavor-pure blocks: one phase only
        const unsigned short* __restrict__ Yf = phase ? Yf1 : Yf0;

        short8 bfr[2][4];
        #pragma unroll
        for (int kc = 0; kc < 4; ++kc)
            bfr[0][kc] = *(const short8*)&Yf[((g0 * 4 + kc) * 64 + lane) * 8];

        #pragma unroll 2
        for (int jt = 0; jt < 16; ++jt) {
            const int cur = jt & 1;
            if (jt < 15) {                        // prefetch next tile's fragments
                const int g = g0 + jt + 1;
                #pragma unroll
                for (int kc = 0; kc < 4; ++kc)
                    bfr[cur ^ 1][kc] = *(const short8*)&Yf[((g * 4 + kc) * 64 + lane) * 8];
            }

            float4v acc[8] = {};
            #pragma unroll
            for (int kc = 0; kc < 4; ++kc)
                #pragma unroll
                for (int rt = 0; rt < 8; ++rt)
                    acc[rt] = __builtin_amdgcn_mfma_f32_16x16x32_bf16(
                        afr[rt][kc], bfr[cur][kc], acc[rt], 0, 0, 0);

            #pragma unroll
            for (int rt = 0; rt < 8; ++rt)
                #pragma unroll
                for (int r = 0; r < 4; ++r)
                    if ((int)((frmask >> (rt * 4 + r)) & 1u) == phase)
                        rowsum[rt][r] += __expf(acc[rt][r] * INV_T - INV_T);
        }
    }

    // reduce over the 16 col-lanes of each quad
    #pragma unroll
    for (int m = 1; m < 16; m <<= 1)
        #pragma unroll
        for (int rt = 0; rt < 8; ++rt)
            #pragma unroll
            for (int r = 0; r < 4; ++r)
                rowsum[rt][r] += __shfl_xor(rowsum[rt][r], m);

    if (mrow == 0) {
        #pragma unroll
        for (int rt = 0; rt < 8; ++rt)
            #pragma unroll
            for (int r = 0; r < 4; ++r)
                atomicAdd(&lAcc[p0 + rt * 16 + quad * 4 + r], rowsum[rt][r]);
    }
}

// ---------------- finish: loss in original row order ----------------
__global__ __launch_bounds__(256) void finish_kernel(
    const float* __restrict__ lAcc, const float* __restrict__ posArr,
    const int* __restrict__ origArr, float* __restrict__ out)
{
    const int p = blockIdx.x * 256 + threadIdx.x;
    out[origArr[p]] = logf(lAcc[p]) + INV_T - posArr[p] * INV_T;
}

// ---------------- launch ----------------
extern "C" void kernel_launch(void* const* d_in, const int* in_sizes, int n_in,
                              void* d_out, int out_size, void* d_ws, size_t ws_size,
                              hipStream_t stream)
{
    const float* fv = (const float*)d_in[0];
    const float* fi = (const float*)d_in[1];
    const float* v  = (const float*)d_in[2];
    const float* vi = (const float*)d_in[3];
    float* out = (float*)d_out;

    unsigned short* Xb  = (unsigned short*)d_ws;   // [B,128] bf16 row-major, compacted X
    unsigned short* Yf0 = Xb  + Bsz * Dd;          // [B*128] bf16, B-fragment-ordered v
    unsigned short* Yf1 = Yf0 + Bsz * Dd;          // [B*128] bf16, B-fragment-ordered vi
    float* posArr = (float*)(Yf1 + Bsz * Dd);      // [B] positive logit (compacted idx)
    float* lAcc   = posArr + Bsz;                  // [B] exp-sum accumulator (compacted idx)
    int*  origArr = (int*)(lAcc + Bsz);            // [B] compacted -> original row
    int*  flagArr = origArr + Bsz;                 // [B] flavor per compacted row
    unsigned long long* cnt = (unsigned long long*)(flagArr + Bsz);

    hipLaunchKernelGGL(init_kernel, dim3(1), dim3(64), 0, stream, cnt);
    hipLaunchKernelGGL(prep_kernel, dim3(Bsz / 16), dim3(1024), 0, stream,
                       fv, fi, v, vi, (unsigned*)Xb, (unsigned*)Yf0, (unsigned*)Yf1,
                       posArr, origArr, flagArr, lAcc, cnt);
    hipLaunchKernelGGL(main_kernel, dim3(Bsz / BM, JSPLIT), dim3(256), 0, stream,
                       Xb, Yf0, Yf1, flagArr, lAcc);
    hipLaunchKernelGGL(finish_kernel, dim3(Bsz / 256), dim3(256), 0, stream,
                       lAcc, posArr, origArr, out);
}

// Round 5
// 107.175 us; speedup vs baseline: 6.9046x; 1.1791x over previous
//
#include <hip/hip_runtime.h>
#include <math.h>

#define Bsz 8192
#define Dd  128
#define BM  64                     // rows per main block
#define NSLICE 8                   // j-slices, keyed to XCD = blockIdx & 7
#define ROT2(x) ((((x) << 2) | ((x) >> 4)) & 63)   // granule bank swizzle

typedef __attribute__((ext_vector_type(8))) short short8;   // 8 bf16 = 4 VGPR
typedef __attribute__((ext_vector_type(4))) float float4v;  // MFMA C/D frag

static constexpr float INV_T = 1.0f / 0.07f;  // logit scale; also fixed logsumexp shift

// RNE float->bf16 pack (x -> low16, y -> high16)
static __device__ inline unsigned pack_bf16(float x, float y) {
    union { float f; unsigned u; } a, b;
    a.f = x; b.f = y;
    unsigned ra = a.u + 0x7FFF + ((a.u >> 16) & 1);
    unsigned rb = b.u + 0x7FFF + ((b.u >> 16) & 1);
    return (ra >> 16) | (rb & 0xFFFF0000u);
}

// ---------------- init: zero the packed compaction counter ----------------
__global__ void init_kernel(unsigned long long* __restrict__ cnt) {
    if (threadIdx.x == 0) cnt[0] = 0ull;
}

// ---------------- prep: 32 rows/block, float4 loads, half-wave butterflies ----
// 1024 threads = 16 waves; wave w owns rows (2w, 2w+1): lane<32 -> row 2w, else 2w+1.
// Lane's c = lane&31 indexes the row's float4 chunk. ONE packed atomic per block.
__global__ __launch_bounds__(1024) void prep_kernel(
    const float4* __restrict__ fv4, const float4* __restrict__ fi4,
    const float4* __restrict__ v4,  const float4* __restrict__ vi4,
    unsigned* __restrict__ Xb, uint2* __restrict__ Yf0, uint2* __restrict__ Yf1,
    float* __restrict__ posArr, int* __restrict__ origArr, int* __restrict__ flagArr,
    float* __restrict__ lAcc, unsigned long long* __restrict__ cnt)
{
    __shared__ unsigned sT0[32 * 66];   // row stride 66 words (even: uint2-aligned)
    __shared__ unsigned sT1[32 * 66];
    __shared__ int sFlagL[32];
    __shared__ int sRank[32];
    __shared__ unsigned sBase[2];

    const int t    = threadIdx.x;
    const int wave = t >> 6;
    const int lane = t & 63;
    const int half = lane >> 5;
    const int c    = lane & 31;
    const int rl   = wave * 2 + half;          // row-local 0..31
    const int b    = blockIdx.x * 32 + rl;     // global row
    const int src  = b * 32 + c;               // float4 index into [B,128]

    const float4 afv = fv4[src];
    const float4 afi = fi4[src];
    const float4 av  = v4[src];
    const float4 avi = vi4[src];

    float nfv = afv.x*afv.x + afv.y*afv.y + afv.z*afv.z + afv.w*afv.w;
    float nfi = afi.x*afi.x + afi.y*afi.y + afi.z*afi.z + afi.w*afi.w;
    float nv  = av.x*av.x   + av.y*av.y   + av.z*av.z   + av.w*av.w;
    float nvi = avi.x*avi.x + avi.y*avi.y + avi.z*avi.z + avi.w*avi.w;
    float dv  = afv.x*av.x  + afv.y*av.y  + afv.z*av.z  + afv.w*av.w;
    float di  = afi.x*avi.x + afi.y*avi.y + afi.z*avi.z + afi.w*avi.w;

    #pragma unroll
    for (int m = 1; m < 32; m <<= 1) {   // half-wave butterfly (rows are 32-lane groups)
        nfv += __shfl_xor(nfv, m);
        nfi += __shfl_xor(nfi, m);
        nv  += __shfl_xor(nv,  m);
        nvi += __shfl_xor(nvi, m);
        dv  += __shfl_xor(dv,  m);
        di  += __shfl_xor(di,  m);
    }

    const float rnfv = 1.0f / fmaxf(sqrtf(nfv), 1e-12f);
    const float rnfi = 1.0f / fmaxf(sqrtf(nfi), 1e-12f);
    const float rnv  = 1.0f / fmaxf(sqrtf(nv ), 1e-12f);
    const float rnvi = 1.0f / fmaxf(sqrtf(nvi), 1e-12f);

    const float pos_v = dv * rnfv * rnv;
    const float pos_i = di * rnfi * rnvi;
    const bool useV = (pos_v >= pos_i);
    const float pos = useV ? pos_v : pos_i;

    // stage normalized Y rows as packed d-pair words for the fragment transpose
    uint2 w0y = make_uint2(pack_bf16(av.x  * rnv,  av.y  * rnv),
                           pack_bf16(av.z  * rnv,  av.w  * rnv));
    uint2 w1y = make_uint2(pack_bf16(avi.x * rnvi, avi.y * rnvi),
                           pack_bf16(avi.z * rnvi, avi.w * rnvi));
    *(uint2*)&sT0[rl * 66 + c * 2] = w0y;
    *(uint2*)&sT1[rl * 66 + c * 2] = w1y;
    if (c == 0) sFlagL[rl] = useV ? 0 : 1;
    __syncthreads();

    // wave 0: block-local ranks + ONE packed 64-bit atomic for both counters
    if (t < 64) {
        const int f = (lane < 32) ? sFlagL[lane] : 2;
        const unsigned long long m0 = __ballot(f == 0);
        const unsigned long long m1 = __ballot(f == 1);
        if (lane == 0) {
            const unsigned long long add =
                (unsigned long long)__popcll(m0) | ((unsigned long long)__popcll(m1) << 32);
            const unsigned long long ret = atomicAdd(cnt, add);
            sBase[0] = (unsigned)(ret & 0xffffffffull);
            sBase[1] = (unsigned)(ret >> 32);
        }
        if (lane < 32) {
            const unsigned long long below = (1ull << lane) - 1ull;
            sRank[lane] = (f == 0) ? (int)__popcll(m0 & below) : (int)__popcll(m1 & below);
        }
    }

    // fragment-ordered Yf write (independent of compaction; overlaps the atomic)
    // uint2 u = blk*1024 + t  <->  words o=2t: tl=t>>9, kc=(t>>7)&3, lp=(t>>1)&63, w0=(t&1)*2
    {
        const int tl = t >> 9;
        const int kc = (t >> 7) & 3;
        const int lp = (t >> 1) & 63;
        const int w0 = (t & 1) * 2;
        const int row = tl * 16 + (lp & 15);
        const int s   = kc * 16 + (lp >> 4) * 4 + w0;   // d-pair word within row
        Yf0[blockIdx.x * 1024 + t] = *(const uint2*)&sT0[row * 66 + s];
        Yf1[blockIdx.x * 1024 + t] = *(const uint2*)&sT1[row * 66 + s];
    }
    __syncthreads();

    const int f  = sFlagL[rl];
    const int rk = sRank[rl];
    const int p  = (f == 0) ? (int)(sBase[0] + rk) : (Bsz - 1 - (int)(sBase[1] + rk));

    const float sc = useV ? rnfv : rnfi;
    ((uint2*)Xb)[p * 32 + c] = make_uint2(pack_bf16(afv.x * sc, afv.y * sc),
                                          pack_bf16(afv.z * sc, afv.w * sc));
    // note: afv/afi selection
    if (!useV)
        ((uint2*)Xb)[p * 32 + c] = make_uint2(pack_bf16(afi.x * sc, afi.y * sc),
                                              pack_bf16(afi.z * sc, afi.w * sc));

    if (c == 0) {
        posArr[p]  = pos;
        origArr[p] = b;
        flagArr[p] = f;
        lAcc[p]    = 0.0f;
    }
}

// ---------------- main: BM=64, XCD-sliced, 4 blocks/CU, split prefetch ----------
// grid 1024 1-D: slice = blk&7 (XCD-keyed j-range), rowblk = blk>>3.
// 4 waves: each owns ALL 64 rows (afr[4][4]) and 16 of the slice's 64 col-tiles.
// A/B frag: [m|n=lane&15][k=quad*8+j]; C/D: col=lane&15, row=quad*4+reg.
__global__ __launch_bounds__(256, 4) void main_kernel(
    const unsigned short* __restrict__ Xb,
    const uint4* __restrict__ Yf0q, const uint4* __restrict__ Yf1q,
    const int* __restrict__ flagArr, float* __restrict__ lAcc)
{
    __shared__ uint4 sXf[1024];        // 16 KB: X fragment-ordered, rot2-swizzled
    __shared__ int sFlag[BM];
    __shared__ int sHas[2];

    const int t    = threadIdx.x;
    const int wave = t >> 6;
    const int lane = t & 63;
    const int quad = lane >> 4;
    const int mrow = lane & 15;
    const int slice = blockIdx.x & 7;
    const int p0    = (blockIdx.x >> 3) * BM;

    if (t < 2) sHas[t] = 0;
    __syncthreads();
    if (t < BM) {
        const int f = flagArr[p0 + t];
        sFlag[t] = f;
        atomicOr(&sHas[f], 1);
    }

    // stage X fragment-ordered with rot2 bank swizzle (conflict-free write+read)
    #pragma unroll
    for (int it = 0; it < 4; ++it) {
        const int i = t + it * 256;
        const int row = i >> 4, ch = i & 15;
        const uint4 val = ((const uint4*)Xb)[(p0 + row) * 16 + ch];
        const int blk16 = (row >> 4) * 4 + (ch >> 2);
        const int slot  = (ch & 3) * 16 + (row & 15);
        sXf[blk16 * 64 + ROT2(slot)] = val;
    }
    __syncthreads();

    // persistent A fragments (slot == lane identity => read at ROT2(lane))
    short8 afr[4][4];
    #pragma unroll
    for (int rt = 0; rt < 4; ++rt)
        #pragma unroll
        for (int kc = 0; kc < 4; ++kc)
            afr[rt][kc] = *(const short8*)&sXf[(rt * 4 + kc) * 64 + ROT2(lane)];

    // row flags: bit rt*4+r for row rt*16+quad*4+r
    unsigned frmask = 0;
    #pragma unroll
    for (int rt = 0; rt < 4; ++rt)
        #pragma unroll
        for (int r = 0; r < 4; ++r)
            frmask |= (unsigned)sFlag[rt * 16 + quad * 4 + r] << (rt * 4 + r);

    float rowsum[4][4] = {};
    const int g0 = slice * 64 + wave * 16;   // first of 16 col-tiles for this wave

    for (int phase = 0; phase < 2; ++phase) {
        if (!sHas[phase]) continue;          // flavor-pure blocks run one phase
        const uint4* __restrict__ yb = (phase ? Yf1q : Yf0q) + (size_t)g0 * 256 + lane;

        short8 b0 = *(const short8*)&yb[0];      // tile g, kc0
        short8 b1 = *(const short8*)&yb[64];     // kc1
        short8 b2 = *(const short8*)&yb[128];    // kc2
        short8 b3 = *(const short8*)&yb[192];    // kc3

        #pragma unroll 1
        for (int jt = 0; jt < 16; ++jt) {
            float4v acc[4] = {};
            #pragma unroll
            for (int rt = 0; rt < 4; ++rt)
                acc[rt] = __builtin_amdgcn_mfma_f32_16x16x32_bf16(afr[rt][0], b0, acc[rt], 0, 0, 0);
            #pragma unroll
            for (int rt = 0; rt < 4; ++rt)
                acc[rt] = __builtin_amdgcn_mfma_f32_16x16x32_bf16(afr[rt][1], b1, acc[rt], 0, 0, 0);
            if (jt < 15) {                       // prefetch next tile kc0/1 (~190cyc early)
                b0 = *(const short8*)&yb[256];
                b1 = *(const short8*)&yb[320];
            }
            #pragma unroll
            for (int rt = 0; rt < 4; ++rt)
                acc[rt] = __builtin_amdgcn_mfma_f32_16x16x32_bf16(afr[rt][2], b2, acc[rt], 0, 0, 0);
            #pragma unroll
            for (int rt = 0; rt < 4; ++rt)
                acc[rt] = __builtin_amdgcn_mfma_f32_16x16x32_bf16(afr[rt][3], b3, acc[rt], 0, 0, 0);
            if (jt < 15) {                       // prefetch next tile kc2/3
                b2 = *(const short8*)&yb[384];
                b3 = *(const short8*)&yb[448];
            }
            yb += 256;

            // fused exp-sum with fixed shift C = 1/T
            #pragma unroll
            for (int rt = 0; rt < 4; ++rt)
                #pragma unroll
                for (int r = 0; r < 4; ++r)
                    if ((int)((frmask >> (rt * 4 + r)) & 1u) == phase)
                        rowsum[rt][r] += __expf(acc[rt][r] * INV_T - INV_T);
        }
    }

    // reduce over the 16 col-lanes of each quad
    #pragma unroll
    for (int m = 1; m < 16; m <<= 1)
        #pragma unroll
        for (int rt = 0; rt < 4; ++rt)
            #pragma unroll
            for (int r = 0; r < 4; ++r)
                rowsum[rt][r] += __shfl_xor(rowsum[rt][r], m);

    if (mrow == 0) {
        #pragma unroll
        for (int rt = 0; rt < 4; ++rt)
            #pragma unroll
            for (int r = 0; r < 4; ++r)
                atomicAdd(&lAcc[p0 + rt * 16 + quad * 4 + r], rowsum[rt][r]);
    }
}

// ---------------- finish: loss in original row order ----------------
__global__ __launch_bounds__(256) void finish_kernel(
    const float* __restrict__ lAcc, const float* __restrict__ posArr,
    const int* __restrict__ origArr, float* __restrict__ out)
{
    const int p = blockIdx.x * 256 + threadIdx.x;
    out[origArr[p]] = logf(lAcc[p]) + INV_T - posArr[p] * INV_T;
}

// ---------------- launch ----------------
extern "C" void kernel_launch(void* const* d_in, const int* in_sizes, int n_in,
                              void* d_out, int out_size, void* d_ws, size_t ws_size,
                              hipStream_t stream)
{
    const float4* fv = (const float4*)d_in[0];
    const float4* fi = (const float4*)d_in[1];
    const float4* v  = (const float4*)d_in[2];
    const float4* vi = (const float4*)d_in[3];
    float* out = (float*)d_out;

    unsigned short* Xb  = (unsigned short*)d_ws;   // [B,128] bf16 row-major, compacted X
    unsigned short* Yf0 = Xb  + Bsz * Dd;          // [B*128] bf16, B-fragment-ordered v
    unsigned short* Yf1 = Yf0 + Bsz * Dd;          // [B*128] bf16, B-fragment-ordered vi
    float* posArr = (float*)(Yf1 + Bsz * Dd);      // [B] positive logit (compacted idx)
    float* lAcc   = posArr + Bsz;                  // [B] exp-sum accumulator
    int*  origArr = (int*)(lAcc + Bsz);            // [B] compacted -> original row
    int*  flagArr = origArr + Bsz;                 // [B] flavor per compacted row
    unsigned long long* cnt = (unsigned long long*)(flagArr + Bsz);

    hipLaunchKernelGGL(init_kernel, dim3(1), dim3(64), 0, stream, cnt);
    hipLaunchKernelGGL(prep_kernel, dim3(Bsz / 32), dim3(1024), 0, stream,
                       fv, fi, v, vi, (unsigned*)Xb, (uint2*)Yf0, (uint2*)Yf1,
                       posArr, origArr, flagArr, lAcc, cnt);
    hipLaunchKernelGGL(main_kernel, dim3((Bsz / BM) * NSLICE), dim3(256), 0, stream,
                       Xb, (const uint4*)Yf0, (const uint4*)Yf1, flagArr, lAcc);
    hipLaunchKernelGGL(finish_kernel, dim3(Bsz / 256), dim3(256), 0, stream,
                       lAcc, posArr, origArr, out);
}